// Round 6
// baseline (1705.696 us; speedup 1.0000x reference)
//
#include <hip/hip_runtime.h>
#include <hip/hip_bf16.h>

typedef unsigned short u16;
typedef unsigned long long u64;
typedef __attribute__((ext_vector_type(8))) short short8x;
typedef __attribute__((ext_vector_type(4))) float f32x4;
typedef __bf16 bf16x8 __attribute__((ext_vector_type(8)));

#define SCALE 0.17677669529663687f

__device__ __forceinline__ u16 f2bf(float f) {
  unsigned u = __builtin_bit_cast(unsigned, f);
  unsigned r = (u + 0x7FFFu + ((u >> 16) & 1u)) >> 16;
  return (u16)r;
}
__device__ __forceinline__ float bf2f(u16 h) {
  return __builtin_bit_cast(float, ((unsigned)h) << 16);
}
__device__ __forceinline__ float gelu_f(float v) {
  float t = v * v;
  float a = __builtin_fmaf(t, -0.07135481627f, -1.59576912161f);
  float e = __expf(v * a);
  return v * __builtin_amdgcn_rcpf(1.0f + e);
}
__device__ __forceinline__ int swz(int row, int col, int ld) {
  return row * ld + ((((col >> 3) ^ (row & 7)) << 3) | (col & 7));
}
__device__ __forceinline__ short8x ldfrag(const u16* s, int row, int kb, int ld) {
  return *(const short8x*)(s + row * ld + (((kb >> 3) ^ (row & 7)) << 3));
}
__device__ __forceinline__ short8x ldg8(const u16* p) { return *(const short8x*)p; }

__device__ __forceinline__ f32x4 MFMA(short8x a, short8x b, f32x4 c) {
  return __builtin_amdgcn_mfma_f32_16x16x32_bf16(
      __builtin_bit_cast(bf16x8, a), __builtin_bit_cast(bf16x8, b), c, 0, 0, 0);
}
__device__ __forceinline__ u64 pack4(float a, float b, float c, float d) {
  return (u64)f2bf(a) | ((u64)f2bf(b) << 16) | ((u64)f2bf(c) << 32) | ((u64)f2bf(d) << 48);
}

// ---------------- weight conversion ----------------
__global__ void cvt_kernel(const float* __restrict__ wqkv, const float* __restrict__ wproj,
                           const float* __restrict__ wfc1, const float* __restrict__ wfc2,
                           const float* __restrict__ c1, const float* __restrict__ c3,
                           const float* __restrict__ c2,
                           u16* oq, u16* op, u16* o1, u16* o2, u16* oc1, u16* oc3,
                           float* ow2r) {
  int i = blockIdx.x * 256 + threadIdx.x;
  if (i < 110592) { float f = wqkv[i]; if (i < 36864) f *= SCALE; oq[i] = f2bf(f); return; }
  i -= 110592;
  if (i < 36864) { op[i] = f2bf(wproj[i]); return; }
  i -= 36864;
  if (i < 147456) { o1[i] = f2bf(wfc1[i]); return; }
  i -= 147456;
  if (i < 147456) { o2[i] = f2bf(wfc2[i]); return; }
  i -= 147456;
  if (i < 6144) { int r = i / 192, c = i - r * 192; oc1[i] = (r < 24) ? f2bf(c1[r * 192 + c]) : (u16)0; return; }
  i -= 6144;
  if (i < 6144) { int cc = i >> 5, k = i & 31; oc3[i] = (k < 24) ? f2bf(c3[cc * 24 + k]) : (u16)0; return; }
  i -= 6144;
  if (i < 5184) { int t = i / 576, rr = i - t * 576; int ci = rr / 24, co = rr - ci * 24;
                  ow2r[i] = c2[co * 216 + ci * 9 + t]; }
}

// ---------------- LN1 (vectorized) ----------------
__global__ __launch_bounds__(256) void ln1_kernel(const float* __restrict__ x,
                                                  const float* __restrict__ g,
                                                  const float* __restrict__ b,
                                                  u16* __restrict__ nx) {
  const int wid = threadIdx.x >> 6, lane = threadIdx.x & 63;
  const int row = blockIdx.x * 4 + wid;
  const float* xr = x + row * 192;
  f32x4 v = {0.f, 0.f, 0.f, 0.f};
  if (lane < 48) v = *(const f32x4*)(xr + lane * 4);
  float s = v[0] + v[1] + v[2] + v[3];
  for (int m = 1; m < 64; m <<= 1) s += __shfl_xor(s, m);
  const float mean = s * (1.0f / 192.0f);
  f32x4 d;
#pragma unroll
  for (int r = 0; r < 4; ++r) d[r] = v[r] - mean;
  float q = (lane < 48) ? (d[0] * d[0] + d[1] * d[1] + d[2] * d[2] + d[3] * d[3]) : 0.f;
  for (int m = 1; m < 64; m <<= 1) q += __shfl_xor(q, m);
  const float rstd = rsqrtf(q * (1.0f / 192.0f) + 1e-5f);
  if (lane < 48) {
    const f32x4 gg = *(const f32x4*)(g + lane * 4);
    const f32x4 bb = *(const f32x4*)(b + lane * 4);
    u64 pk = pack4(d[0] * rstd * gg[0] + bb[0], d[1] * rstd * gg[1] + bb[1],
                   d[2] * rstd * gg[2] + bb[2], d[3] * rstd * gg[3] + bb[3]);
    *(u64*)(nx + row * 192 + lane * 4) = pk;
  }
}

// ---------------- fused shifted-window attention (8 waves, balanced phases) ----------------
__global__ __launch_bounds__(512, 4) void attn_kernel(
    const float* __restrict__ x, const u16* __restrict__ nx,
    const u16* __restrict__ wq, const float* __restrict__ bqkv,
    const float* __restrict__ rel, const u16* __restrict__ wp,
    const float* __restrict__ bproj, u16* __restrict__ vT,
    float* __restrict__ x1out) {
  __shared__ u16 sQK[64 * 384];
  __shared__ float sRel[1350];
  __shared__ int sG[64];

  const int tid = threadIdx.x, blk = blockIdx.x;
  const int b = blk >> 10, wi = (blk >> 5) & 31, wj = blk & 31;
  const int wv = tid >> 6, lane = tid & 63, lr = lane & 15, hi = lane >> 4;
  u16* vTw = vT + blk * 12288;

  for (int i = tid; i < 1350; i += 512) sRel[i] = rel[i];
  if (tid < 64) {
    int si = (wi * 8 + (tid >> 3) + 4) & 255, sj = (wj * 8 + (tid & 7) + 4) & 255;
    sG[tid] = b * 65536 + si * 256 + sj;
  }
  for (int i = tid; i < 64 * 96; i += 512) {
    int r = i / 96, w32 = i - r * 96;
    int si = (wi * 8 + (r >> 3) + 4) & 255, sj = (wj * 8 + (r & 7) + 4) & 255;
    int grow = b * 65536 + si * 256 + sj;
    unsigned v = ((const unsigned*)nx)[grow * 96 + w32];
    ((unsigned*)sQK)[r * 192 + ((((w32 >> 2) ^ (r & 7)) << 2) | (w32 & 3))] = v;
  }
  __syncthreads();

  // ---- P1: QKV. waves 0-5: Q,K flipped (64 cols each); waves 6-7: V normal (96 cols each)
  f32x4 acc[4][4] = {};
  if (wv < 6) {
    const int wbase = wv * 64;
#pragma unroll
    for (int kk = 0; kk < 6; ++kk) {
      short8x Xf[4];
#pragma unroll
      for (int tt = 0; tt < 4; ++tt) Xf[tt] = ldfrag(sQK, tt * 16 + lr, kk * 32 + hi * 8, 384);
#pragma unroll
      for (int wt = 0; wt < 4; ++wt) {
        short8x Wf = ldg8(wq + (wbase + wt * 16 + lr) * 192 + kk * 32 + hi * 8);
#pragma unroll
        for (int tt = 0; tt < 4; ++tt) acc[wt][tt] = MFMA(Wf, Xf[tt], acc[wt][tt]);
      }
    }
  } else {
    const int vbase = (wv - 6) * 96;
    float bv[6];
#pragma unroll
    for (int nt = 0; nt < 6; ++nt) bv[nt] = bqkv[384 + vbase + nt * 16 + lr];
#pragma unroll
    for (int mt = 0; mt < 4; ++mt) {
      f32x4 vacc[6] = {};
#pragma unroll
      for (int kk = 0; kk < 6; ++kk) {
        short8x A = ldfrag(sQK, mt * 16 + lr, kk * 32 + hi * 8, 384);
#pragma unroll
        for (int nt = 0; nt < 6; ++nt)
          vacc[nt] = MFMA(A, ldg8(wq + (384 + vbase + nt * 16 + lr) * 192 + kk * 32 + hi * 8), vacc[nt]);
      }
#pragma unroll
      for (int nt = 0; nt < 6; ++nt) {
        u64 pk = pack4(vacc[nt][0] + bv[nt], vacc[nt][1] + bv[nt],
                       vacc[nt][2] + bv[nt], vacc[nt][3] + bv[nt]);
        *(u64*)(vTw + (vbase + nt * 16 + lr) * 64 + mt * 16 + hi * 4) = pk;
      }
    }
  }
  __syncthreads();

  // ---- P2: write Q,K into sQK (flipped layout: row=token, 4 consecutive ocols per lane)
  if (wv < 6) {
    const int wbase = wv * 64;
#pragma unroll
    for (int wt = 0; wt < 4; ++wt) {
      const int oc0 = wbase + wt * 16 + hi * 4;
      const f32x4 bq = *(const f32x4*)(bqkv + oc0);
      const float sc = (oc0 < 192) ? SCALE : 1.0f;
#pragma unroll
      for (int tt = 0; tt < 4; ++tt) {
        u64 pk = pack4(acc[wt][tt][0] + bq[0] * sc, acc[wt][tt][1] + bq[1] * sc,
                       acc[wt][tt][2] + bq[2] * sc, acc[wt][tt][3] + bq[3] * sc);
        *(u64*)&sQK[swz(tt * 16 + lr, oc0, 384)] = pk;
      }
    }
  }
  __syncthreads();

  // ---- P3: 24 slices (head h, row-quarter q), 3 per wave ----
  f32x4 S[3][4];
#pragma unroll
  for (int i = 0; i < 3; ++i) {
    const int s = wv + 8 * i, h3 = s >> 2, q = s & 3;
    short8x Aq = ldfrag(sQK, q * 16 + lr, h3 * 32 + hi * 8, 384);
#pragma unroll
    for (int nt = 0; nt < 4; ++nt) {
      short8x Bk = ldfrag(sQK, nt * 16 + lr, 192 + h3 * 32 + hi * 8, 384);
      S[i][nt] = MFMA(Aq, Bk, (f32x4){0.f, 0.f, 0.f, 0.f});
    }
#pragma unroll
    for (int r = 0; r < 4; ++r) {
      const int tI = q * 16 + hi * 4 + r;
      const int tri = tI >> 3, trj = tI & 7;
      const int ui = wi * 8 + tri, vi = wj * 8 + trj;
      const int rgi = (ui >= 248) + (ui >= 252), cgi = (vi >= 248) + (vi >= 252);
#pragma unroll
      for (int nt = 0; nt < 4; ++nt) {
        const int tJ = nt * 16 + lr;
        const int tci = tJ >> 3, tcj = tJ & 7;
        const int idx = (tri - tci + 7) * 15 + (trj - tcj + 7);
        float v = S[i][nt][r] + sRel[idx * 6 + h3];
        const int uj = wi * 8 + tci, vj = wj * 8 + tcj;
        const int rgj = (uj >= 248) + (uj >= 252), cgj = (vj >= 248) + (vj >= 252);
        if ((rgi != rgj) | (cgi != cgj)) v -= 100.0f;
        S[i][nt][r] = v;
      }
    }
#pragma unroll
    for (int r = 0; r < 4; ++r) {
      float mx = fmaxf(fmaxf(S[i][0][r], S[i][1][r]), fmaxf(S[i][2][r], S[i][3][r]));
      mx = fmaxf(mx, __shfl_xor(mx, 1));
      mx = fmaxf(mx, __shfl_xor(mx, 2));
      mx = fmaxf(mx, __shfl_xor(mx, 4));
      mx = fmaxf(mx, __shfl_xor(mx, 8));
      float sm = 0.f;
#pragma unroll
      for (int nt = 0; nt < 4; ++nt) { float e = __expf(S[i][nt][r] - mx); S[i][nt][r] = e; sm += e; }
      sm += __shfl_xor(sm, 1); sm += __shfl_xor(sm, 2);
      sm += __shfl_xor(sm, 4); sm += __shfl_xor(sm, 8);
      const float inv = 1.0f / sm;
#pragma unroll
      for (int nt = 0; nt < 4; ++nt) S[i][nt][r] *= inv;
    }
  }
  __syncthreads();  // all Q/K reads done

  // P write over Q,K region: P_h = [64 tok][64 key] at h*4096, swizzled ld=64
#pragma unroll
  for (int i = 0; i < 3; ++i) {
    const int s = wv + 8 * i, h3 = s >> 2, q = s & 3;
#pragma unroll
    for (int r = 0; r < 4; ++r)
#pragma unroll
      for (int nt = 0; nt < 4; ++nt)
        sQK[h3 * 4096 + swz(q * 16 + hi * 4 + r, nt * 16 + lr, 64)] = f2bf(S[i][nt][r]);
  }
  __syncthreads();

  // ---- P4: PV, 24 tiles (h, dcol-tile, tok-half), 3 per wave, flipped ----
  f32x4 oacc[3][2] = {};
#pragma unroll
  for (int i = 0; i < 3; ++i) {
    const int t = wv + 8 * i, h3 = t >> 2, dt = (t >> 1) & 1, tth = t & 1;
#pragma unroll
    for (int kk = 0; kk < 2; ++kk) {
      short8x Va = ldg8(vTw + (h3 * 32 + dt * 16 + lr) * 64 + kk * 32 + hi * 8);
#pragma unroll
      for (int t2 = 0; t2 < 2; ++t2) {
        short8x Pf = ldfrag(sQK + h3 * 4096, tth * 32 + t2 * 16 + lr, kk * 32 + hi * 8, 64);
        oacc[i][t2] = MFMA(Va, Pf, oacc[i][t2]);
      }
    }
  }
  __syncthreads();  // PV reads of P done

  // attn-out over P region: [64 tok][192 dcol] swizzled, b64 packed
#pragma unroll
  for (int i = 0; i < 3; ++i) {
    const int t = wv + 8 * i, h3 = t >> 2, dt = (t >> 1) & 1, tth = t & 1;
#pragma unroll
    for (int t2 = 0; t2 < 2; ++t2) {
      u64 pk = pack4(oacc[i][t2][0], oacc[i][t2][1], oacc[i][t2][2], oacc[i][t2][3]);
      *(u64*)&sQK[swz(tth * 32 + t2 * 16 + lr, h3 * 32 + dt * 16 + hi * 4, 192)] = pk;
    }
  }
  __syncthreads();

  // ---- P6: proj flipped + residual -> x1out. 12 wtiles over 8 waves
  {
    const int nw = (wv < 4) ? 2 : 1;
    const int wt0 = (wv < 4) ? wv * 2 : (4 + wv);
    f32x4 pacc[2][4] = {};
#pragma unroll
    for (int kk = 0; kk < 6; ++kk) {
      short8x Of[4];
#pragma unroll
      for (int tt = 0; tt < 4; ++tt) Of[tt] = ldfrag(sQK, tt * 16 + lr, kk * 32 + hi * 8, 192);
      for (int w2 = 0; w2 < nw; ++w2) {
        short8x Wp = ldg8(wp + ((wt0 + w2) * 16 + lr) * 192 + kk * 32 + hi * 8);
#pragma unroll
        for (int tt = 0; tt < 4; ++tt) pacc[w2][tt] = MFMA(Wp, Of[tt], pacc[w2][tt]);
      }
    }
    for (int w2 = 0; w2 < nw; ++w2) {
      const int oc0 = (wt0 + w2) * 16 + hi * 4;
      const f32x4 bb = *(const f32x4*)(bproj + oc0);
#pragma unroll
      for (int tt = 0; tt < 4; ++tt) {
        const int grow = sG[tt * 16 + lr];
        const f32x4 xv = *(const f32x4*)(x + grow * 192 + oc0);
        f32x4 o;
#pragma unroll
        for (int r = 0; r < 4; ++r) o[r] = xv[r] + pacc[w2][tt][r] + bb[r];
        *(f32x4*)(x1out + grow * 192 + oc0) = o;
      }
    }
  }
}

// ---------------- conv1 (1x1, 192->24 padded 32), MFMA ----------------
__global__ __launch_bounds__(256) void conv1_kernel(const u16* __restrict__ nx,
                                                    const u16* __restrict__ w1,
                                                    const float* __restrict__ b1,
                                                    float* __restrict__ y1) {
  const int tid = threadIdx.x, wv = tid >> 6, lane = tid & 63, lr = lane & 15, hi = lane >> 4;
  const int g0 = blockIdx.x * 64;
  const int mt = wv;
  short8x Af[6];
#pragma unroll
  for (int kk = 0; kk < 6; ++kk)
    Af[kk] = ldg8(nx + (g0 + mt * 16 + lr) * 192 + kk * 32 + hi * 8);
  const int bI = g0 >> 16;
  const int hw0 = g0 & 65535;
#pragma unroll
  for (int nt = 0; nt < 2; ++nt) {
    f32x4 acc = {0.f, 0.f, 0.f, 0.f};
#pragma unroll
    for (int kk = 0; kk < 6; ++kk) {
      short8x Bf = ldg8(w1 + (nt * 16 + lr) * 192 + kk * 32 + hi * 8);
      acc = MFMA(Af[kk], Bf, acc);
    }
    const int c = nt * 16 + lr;
    if (c < 24) {
      const float bb = b1[c];
#pragma unroll
      for (int r = 0; r < 4; ++r) {
        const int pix = hw0 + mt * 16 + hi * 4 + r;
        y1[(bI * 24 + c) * 65536 + pix] = acc[r] + bb;
      }
    }
  }
}

// ---------------- conv2 (3x3, 24->24), VALU ----------------
__global__ __launch_bounds__(256) void conv2_kernel(const float* __restrict__ y1,
                                                    const float* __restrict__ w2r,
                                                    const float* __restrict__ cb2,
                                                    u16* __restrict__ y2) {
  const int j = threadIdx.x;
  const int i = blockIdx.x & 255;
  const int b = blockIdx.x >> 8;
  float acc[24];
#pragma unroll
  for (int r = 0; r < 24; ++r) acc[r] = cb2[r];
  const float* base = y1 + b * 24 * 65536;
  for (int t = 0; t < 9; ++t) {
    const int dh = t / 3 - 1, dw = t % 3 - 1;
    const int ii = i + dh, jj = j + dw;
    const bool ok = (ii >= 0) & (ii < 256) & (jj >= 0) & (jj < 256);
    const int offc = ok ? (ii * 256 + jj) : 0;
    const float* wt = w2r + t * 576;
    float v[24];
#pragma unroll
    for (int ci = 0; ci < 24; ++ci) {
      float vv = base[ci * 65536 + offc];
      v[ci] = ok ? vv : 0.0f;
    }
#pragma unroll
    for (int ci = 0; ci < 24; ++ci)
#pragma unroll
      for (int co = 0; co < 24; ++co)
        acc[co] += v[ci] * wt[ci * 24 + co];
  }
  u16* o = y2 + (b * 65536 + i * 256 + j) * 32;
#pragma unroll
  for (int r = 0; r < 24; ++r) o[r] = f2bf(acc[r]);
  ((unsigned long long*)(o + 24))[0] = 0ull;
  ((unsigned long long*)(o + 24))[1] = 0ull;
}

// ---------------- conv3 (1x1, 24->192) + LeakyReLU + pooled sums ----------------
__global__ __launch_bounds__(256) void conv3_kernel(const u16* __restrict__ y2,
                                                    const u16* __restrict__ w3,
                                                    const float* __restrict__ b3,
                                                    u16* __restrict__ y,
                                                    float* __restrict__ pooled) {
  const int tid = threadIdx.x, wv = tid >> 6, lane = tid & 63, lr = lane & 15, hi = lane >> 4;
  const int g0 = blockIdx.x * 64;
  short8x Af[4];
#pragma unroll
  for (int mt = 0; mt < 4; ++mt)
    Af[mt] = ldg8(y2 + (g0 + mt * 16 + lr) * 32 + hi * 8);
  const int bI = g0 >> 16;
#pragma unroll
  for (int nt0 = 0; nt0 < 3; ++nt0) {
    const int c = (wv * 3 + nt0) * 16 + lr;
    short8x Bf = ldg8(w3 + c * 32 + hi * 8);
    const float bb = b3[c];
    float colsum = 0.f;
#pragma unroll
    for (int mt = 0; mt < 4; ++mt) {
      f32x4 acc = {0.f, 0.f, 0.f, 0.f};
      acc = MFMA(Af[mt], Bf, acc);
#pragma unroll
      for (int r = 0; r < 4; ++r) {
        float v = acc[r] + bb;
        v = (v >= 0.f) ? v : 0.2f * v;
        y[(g0 + mt * 16 + hi * 4 + r) * 192 + c] = f2bf(v);
        colsum += v;
      }
    }
    colsum += __shfl_xor(colsum, 16);
    colsum += __shfl_xor(colsum, 32);
    if (hi == 0) atomicAdd(&pooled[bI * 192 + c], colsum);
  }
}

// ---------------- SE gate ----------------
__global__ void se_kernel(const float* __restrict__ pooled, const float* __restrict__ w1,
                          const float* __restrict__ w2, float* __restrict__ wgt) {
  __shared__ float t[24];
  const int b = blockIdx.x, lane = threadIdx.x;
  if (lane < 24) {
    float s = 0.f;
    for (int c = 0; c < 192; ++c) s += pooled[b * 192 + c] * (1.0f / 65536.0f) * w1[lane * 192 + c];
    t[lane] = fmaxf(s, 0.0f);
  }
  __syncthreads();
  for (int c = lane; c < 192; c += 64) {
    float s = 0.f;
#pragma unroll
    for (int r = 0; r < 24; ++r) s += t[r] * w2[c * 24 + r];
    wgt[b * 192 + c] = 1.0f / (1.0f + __expf(-s));
  }
}

// ---------------- fused LN2 + MLP + residual + LCE add ----------------
// 32 rows/block, 6 waves, 24 KB LDS total (occupancy experiment: granule-32 -> 4-5 blocks/CU).
// FC1 flipped (wave owns 32 hidden): 2 ds -> 4 MFMA. FC2 flipped (wave = 16-token half x 4 oc-tiles).
__global__ __launch_bounds__(384, 6) void mlp_kernel(
    const float* x1, const float* __restrict__ g2, const float* __restrict__ b2,
    const u16* __restrict__ w1m, const float* __restrict__ bf1,
    const u16* __restrict__ w2m, const float* __restrict__ bf2,
    const u16* __restrict__ y, const float* __restrict__ wgt, float* out) {
  __shared__ u16 sN[32 * 192];
  __shared__ u16 sH[32 * 192];
  const int tid = threadIdx.x, wv = tid >> 6, lane = tid & 63, lr = lane & 15, hi = lane >> 4;
  const int g0 = blockIdx.x * 32;

  for (int row = wv; row < 32; row += 6) {
    const float* xr = x1 + (g0 + row) * 192;
    f32x4 v = {0.f, 0.f, 0.f, 0.f};
    if (lane < 48) v = *(const f32x4*)(xr + lane * 4);
    float s = v[0] + v[1] + v[2] + v[3];
    for (int m = 1; m < 64; m <<= 1) s += __shfl_xor(s, m);
    const float mean = s * (1.0f / 192.0f);
    f32x4 d;
#pragma unroll
    for (int r = 0; r < 4; ++r) d[r] = v[r] - mean;
    float q = (lane < 48) ? (d[0] * d[0] + d[1] * d[1] + d[2] * d[2] + d[3] * d[3]) : 0.f;
    for (int m = 1; m < 64; m <<= 1) q += __shfl_xor(q, m);
    const float rstd = rsqrtf(q * (1.0f / 192.0f) + 1e-5f);
    if (lane < 48) {
      const f32x4 gg = *(const f32x4*)(g2 + lane * 4);
      const f32x4 bb = *(const f32x4*)(b2 + lane * 4);
      u64 pk = pack4(d[0] * rstd * gg[0] + bb[0], d[1] * rstd * gg[1] + bb[1],
                     d[2] * rstd * gg[2] + bb[2], d[3] * rstd * gg[3] + bb[3]);
      *(u64*)&sN[swz(row, lane * 4, 192)] = pk;
    }
  }
  __syncthreads();

  const int tt_w = (wv >= 3) ? 1 : 0;     // token half owned in FC2
  const int ww = wv - 3 * tt_w;           // oc-tile group {ww, ww+3, ww+6, ww+9}
  f32x4 acc2[4] = {};
  for (int c = 0; c < 4; ++c) {
    // FC1 flipped: wave owns 32 hidden cols of the 192-chunk
    f32x4 acc1[2][2] = {};
#pragma unroll
    for (int kk = 0; kk < 6; ++kk) {
      short8x Xf0 = ldfrag(sN, lr, kk * 32 + hi * 8, 192);
      short8x Xf1 = ldfrag(sN, 16 + lr, kk * 32 + hi * 8, 192);
#pragma unroll
      for (int wt = 0; wt < 2; ++wt) {
        short8x Wf = ldg8(w1m + (c * 192 + wv * 32 + wt * 16 + lr) * 192 + kk * 32 + hi * 8);
        acc1[wt][0] = MFMA(Wf, Xf0, acc1[wt][0]);
        acc1[wt][1] = MFMA(Wf, Xf1, acc1[wt][1]);
      }
    }
    if (c) __syncthreads();  // FC2(c-1) readers done before overwriting sH
#pragma unroll
    for (int wt = 0; wt < 2; ++wt) {
      const int h0 = c * 192 + wv * 32 + wt * 16 + hi * 4;
      const f32x4 b1v = *(const f32x4*)(bf1 + h0);
#pragma unroll
      for (int tt = 0; tt < 2; ++tt) {
        u64 pk = pack4(gelu_f(acc1[wt][tt][0] + b1v[0]), gelu_f(acc1[wt][tt][1] + b1v[1]),
                       gelu_f(acc1[wt][tt][2] + b1v[2]), gelu_f(acc1[wt][tt][3] + b1v[3]));
        *(u64*)&sH[swz(tt * 16 + lr, wv * 32 + wt * 16 + hi * 4, 192)] = pk;
      }
    }
    __syncthreads();
    // FC2 flipped partial: 1 Hf ds -> 4 MFMA (4 oc-tiles)
#pragma unroll
    for (int kk = 0; kk < 6; ++kk) {
      short8x Hf = ldfrag(sH, tt_w * 16 + lr, kk * 32 + hi * 8, 192);
#pragma unroll
      for (int j = 0; j < 4; ++j) {
        short8x W2 = ldg8(w2m + ((ww + 3 * j) * 16 + lr) * 768 + c * 192 + kk * 32 + hi * 8);
        acc2[j] = MFMA(W2, Hf, acc2[j]);
      }
    }
  }

  const int bI = g0 >> 16;
  const int grow = g0 + tt_w * 16 + lr;
#pragma unroll
  for (int j = 0; j < 4; ++j) {
    const int oc0 = (ww + 3 * j) * 16 + hi * 4;
    const f32x4 bb = *(const f32x4*)(bf2 + oc0);
    const f32x4 wg = *(const f32x4*)(wgt + bI * 192 + oc0);
    const f32x4 xv = *(const f32x4*)(x1 + grow * 192 + oc0);
    const u64 yv = *(const u64*)(y + grow * 192 + oc0);
    f32x4 o;
#pragma unroll
    for (int r = 0; r < 4; ++r)
      o[r] = xv[r] + acc2[j][r] + bb[r] + bf2f((u16)(yv >> (16 * r))) * wg[r];
    *(f32x4*)(out + grow * 192 + oc0) = o;
  }
}

extern "C" void kernel_launch(void* const* d_in, const int* in_sizes, int n_in,
                              void* d_out, int out_size, void* d_ws, size_t ws_size,
                              hipStream_t stream) {
  const float* x     = (const float*)d_in[0];
  const float* ln1g  = (const float*)d_in[1];
  const float* ln1b  = (const float*)d_in[2];
  const float* wqkv  = (const float*)d_in[3];
  const float* bqkv  = (const float*)d_in[4];
  const float* rel   = (const float*)d_in[5];
  const float* wproj = (const float*)d_in[6];
  const float* bproj = (const float*)d_in[7];
  const float* ln2g  = (const float*)d_in[8];
  const float* ln2b  = (const float*)d_in[9];
  const float* wfc1  = (const float*)d_in[10];
  const float* bfc1  = (const float*)d_in[11];
  const float* wfc2  = (const float*)d_in[12];
  const float* bfc2  = (const float*)d_in[13];
  const float* c1w   = (const float*)d_in[14];
  const float* c1b   = (const float*)d_in[15];
  const float* c2w   = (const float*)d_in[16];
  const float* c2b   = (const float*)d_in[17];
  const float* c3w   = (const float*)d_in[18];
  const float* c3b   = (const float*)d_in[19];
  const float* sew1  = (const float*)d_in[20];
  const float* sew2  = (const float*)d_in[21];

  char* ws = (char*)d_ws;
  u16*   nx   = (u16*)(ws + 0);
  float* y1   = (float*)(ws + 100663296);
  u16*   y2   = (u16*)(ws + 125829120);
  u16*   yb   = (u16*)(ws + 142606336);   // LCE output; ALSO reused as vT during attn (attn < conv3)
  u16*   wq   = (u16*)(ws + 243269632);
  u16*   wp   = (u16*)(ws + 243490816);
  u16*   w1m  = (u16*)(ws + 243564544);
  u16*   w2m  = (u16*)(ws + 243859456);
  u16*   cw1  = (u16*)(ws + 244154368);
  u16*   cw3  = (u16*)(ws + 244166656);
  float* w2r  = (float*)(ws + 244178944);
  float* pool = (float*)(ws + 244199680);
  float* wgt  = (float*)(ws + 244202752);
  float* out  = (float*)d_out;
  u16*   vT   = yb;

  hipMemsetAsync(pool, 0, 3072, stream);
  cvt_kernel<<<1797, 256, 0, stream>>>(wqkv, wproj, wfc1, wfc2, c1w, c3w, c2w,
                                       wq, wp, w1m, w2m, cw1, cw3, w2r);
  ln1_kernel<<<65536, 256, 0, stream>>>(x, ln1g, ln1b, nx);
  attn_kernel<<<4096, 512, 0, stream>>>(x, nx, wq, bqkv, rel, wp, bproj, vT, out);
  conv1_kernel<<<4096, 256, 0, stream>>>(nx, cw1, c1b, y1);
  conv2_kernel<<<1024, 256, 0, stream>>>(y1, w2r, c2b, y2);
  conv3_kernel<<<4096, 256, 0, stream>>>(y2, cw3, c3b, yb, pool);
  se_kernel<<<4, 64, 0, stream>>>(pool, sew1, sew2, wgt);
  mlp_kernel<<<8192, 384, 0, stream>>>(out, ln2g, ln2b, w1m, bfc1, w2m, bfc2, yb, wgt, out);
}

// Round 7
// 1015.236 us; speedup vs baseline: 1.6801x; 1.6801x over previous
//
#include <hip/hip_runtime.h>
#include <hip/hip_bf16.h>

typedef unsigned short u16;
typedef unsigned long long u64;
typedef __attribute__((ext_vector_type(8))) short short8x;
typedef __attribute__((ext_vector_type(4))) float f32x4;
typedef __bf16 bf16x8 __attribute__((ext_vector_type(8)));

#define SCALE 0.17677669529663687f

__device__ __forceinline__ u16 f2bf(float f) {
  unsigned u = __builtin_bit_cast(unsigned, f);
  unsigned r = (u + 0x7FFFu + ((u >> 16) & 1u)) >> 16;
  return (u16)r;
}
__device__ __forceinline__ float bf2f(u16 h) {
  return __builtin_bit_cast(float, ((unsigned)h) << 16);
}
__device__ __forceinline__ float gelu_f(float v) {
  float t = v * v;
  float a = __builtin_fmaf(t, -0.07135481627f, -1.59576912161f);
  float e = __expf(v * a);
  return v * __builtin_amdgcn_rcpf(1.0f + e);
}
__device__ __forceinline__ int swz(int row, int col, int ld) {
  return row * ld + ((((col >> 3) ^ (row & 7)) << 3) | (col & 7));
}
__device__ __forceinline__ short8x ldfrag(const u16* s, int row, int kb, int ld) {
  return *(const short8x*)(s + row * ld + (((kb >> 3) ^ (row & 7)) << 3));
}
__device__ __forceinline__ short8x ldg8(const u16* p) { return *(const short8x*)p; }

__device__ __forceinline__ f32x4 MFMA(short8x a, short8x b, f32x4 c) {
  return __builtin_amdgcn_mfma_f32_16x16x32_bf16(
      __builtin_bit_cast(bf16x8, a), __builtin_bit_cast(bf16x8, b), c, 0, 0, 0);
}
__device__ __forceinline__ u64 pack4(float a, float b, float c, float d) {
  return (u64)f2bf(a) | ((u64)f2bf(b) << 16) | ((u64)f2bf(c) << 32) | ((u64)f2bf(d) << 48);
}

// ---------------- weight conversion ----------------
__global__ void cvt_kernel(const float* __restrict__ wqkv, const float* __restrict__ wproj,
                           const float* __restrict__ wfc1, const float* __restrict__ wfc2,
                           const float* __restrict__ c1, const float* __restrict__ c3,
                           const float* __restrict__ c2,
                           u16* oq, u16* op, u16* o1, u16* o2, u16* oc1, u16* oc3,
                           float* ow2r) {
  int i = blockIdx.x * 256 + threadIdx.x;
  if (i < 110592) { float f = wqkv[i]; if (i < 36864) f *= SCALE; oq[i] = f2bf(f); return; }
  i -= 110592;
  if (i < 36864) { op[i] = f2bf(wproj[i]); return; }
  i -= 36864;
  if (i < 147456) { o1[i] = f2bf(wfc1[i]); return; }
  i -= 147456;
  if (i < 147456) { o2[i] = f2bf(wfc2[i]); return; }
  i -= 147456;
  if (i < 6144) { int r = i / 192, c = i - r * 192; oc1[i] = (r < 24) ? f2bf(c1[r * 192 + c]) : (u16)0; return; }
  i -= 6144;
  if (i < 6144) { int cc = i >> 5, k = i & 31; oc3[i] = (k < 24) ? f2bf(c3[cc * 24 + k]) : (u16)0; return; }
  i -= 6144;
  if (i < 5184) { int t = i / 576, rr = i - t * 576; int ci = rr / 24, co = rr - ci * 24;
                  ow2r[i] = c2[co * 216 + ci * 9 + t]; }
}

// ---------------- LN1 (vectorized) ----------------
__global__ __launch_bounds__(256) void ln1_kernel(const float* __restrict__ x,
                                                  const float* __restrict__ g,
                                                  const float* __restrict__ b,
                                                  u16* __restrict__ nx) {
  const int wid = threadIdx.x >> 6, lane = threadIdx.x & 63;
  const int row = blockIdx.x * 4 + wid;
  const float* xr = x + row * 192;
  f32x4 v = {0.f, 0.f, 0.f, 0.f};
  if (lane < 48) v = *(const f32x4*)(xr + lane * 4);
  float s = v[0] + v[1] + v[2] + v[3];
  for (int m = 1; m < 64; m <<= 1) s += __shfl_xor(s, m);
  const float mean = s * (1.0f / 192.0f);
  f32x4 d;
#pragma unroll
  for (int r = 0; r < 4; ++r) d[r] = v[r] - mean;
  float q = (lane < 48) ? (d[0] * d[0] + d[1] * d[1] + d[2] * d[2] + d[3] * d[3]) : 0.f;
  for (int m = 1; m < 64; m <<= 1) q += __shfl_xor(q, m);
  const float rstd = rsqrtf(q * (1.0f / 192.0f) + 1e-5f);
  if (lane < 48) {
    const f32x4 gg = *(const f32x4*)(g + lane * 4);
    const f32x4 bb = *(const f32x4*)(b + lane * 4);
    u64 pk = pack4(d[0] * rstd * gg[0] + bb[0], d[1] * rstd * gg[1] + bb[1],
                   d[2] * rstd * gg[2] + bb[2], d[3] * rstd * gg[3] + bb[3]);
    *(u64*)(nx + row * 192 + lane * 4) = pk;
  }
}

// ---------------- fused shifted-window attention (8 waves, balanced phases) ----------------
__global__ __launch_bounds__(512, 4) void attn_kernel(
    const float* __restrict__ x, const u16* __restrict__ nx,
    const u16* __restrict__ wq, const float* __restrict__ bqkv,
    const float* __restrict__ rel, const u16* __restrict__ wp,
    const float* __restrict__ bproj, u16* __restrict__ vT,
    float* __restrict__ x1out) {
  __shared__ u16 sQK[64 * 384];
  __shared__ float sRel[1350];
  __shared__ int sG[64];

  const int tid = threadIdx.x, blk = blockIdx.x;
  const int b = blk >> 10, wi = (blk >> 5) & 31, wj = blk & 31;
  const int wv = tid >> 6, lane = tid & 63, lr = lane & 15, hi = lane >> 4;
  u16* vTw = vT + blk * 12288;

  for (int i = tid; i < 1350; i += 512) sRel[i] = rel[i];
  if (tid < 64) {
    int si = (wi * 8 + (tid >> 3) + 4) & 255, sj = (wj * 8 + (tid & 7) + 4) & 255;
    sG[tid] = b * 65536 + si * 256 + sj;
  }
  for (int i = tid; i < 64 * 96; i += 512) {
    int r = i / 96, w32 = i - r * 96;
    int si = (wi * 8 + (r >> 3) + 4) & 255, sj = (wj * 8 + (r & 7) + 4) & 255;
    int grow = b * 65536 + si * 256 + sj;
    unsigned v = ((const unsigned*)nx)[grow * 96 + w32];
    ((unsigned*)sQK)[r * 192 + ((((w32 >> 2) ^ (r & 7)) << 2) | (w32 & 3))] = v;
  }
  __syncthreads();

  // ---- P1: QKV. waves 0-5: Q,K flipped (64 cols each); waves 6-7: V (96 cols each, weights hoisted)
  f32x4 acc[4][4] = {};
  if (wv < 6) {
    const int wbase = wv * 64;
#pragma unroll
    for (int kk = 0; kk < 6; ++kk) {
      short8x Xf[4];
#pragma unroll
      for (int tt = 0; tt < 4; ++tt) Xf[tt] = ldfrag(sQK, tt * 16 + lr, kk * 32 + hi * 8, 384);
#pragma unroll
      for (int wt = 0; wt < 4; ++wt) {
        short8x Wf = ldg8(wq + (wbase + wt * 16 + lr) * 192 + kk * 32 + hi * 8);
#pragma unroll
        for (int tt = 0; tt < 4; ++tt) acc[wt][tt] = MFMA(Wf, Xf[tt], acc[wt][tt]);
      }
    }
  } else {
    const int vbase = (wv - 6) * 96;
#pragma unroll
    for (int half = 0; half < 2; ++half) {
      short8x Bf[3][6];
      float bv[3];
#pragma unroll
      for (int j = 0; j < 3; ++j) {
        const int vc = vbase + (half * 3 + j) * 16 + lr;
#pragma unroll
        for (int kk = 0; kk < 6; ++kk)
          Bf[j][kk] = ldg8(wq + (384 + vc) * 192 + kk * 32 + hi * 8);
        bv[j] = bqkv[384 + vc];
      }
#pragma unroll
      for (int mt = 0; mt < 4; ++mt) {
        f32x4 vacc[3] = {};
#pragma unroll
        for (int kk = 0; kk < 6; ++kk) {
          short8x A = ldfrag(sQK, mt * 16 + lr, kk * 32 + hi * 8, 384);
#pragma unroll
          for (int j = 0; j < 3; ++j) vacc[j] = MFMA(A, Bf[j][kk], vacc[j]);
        }
#pragma unroll
        for (int j = 0; j < 3; ++j) {
          u64 pk = pack4(vacc[j][0] + bv[j], vacc[j][1] + bv[j],
                         vacc[j][2] + bv[j], vacc[j][3] + bv[j]);
          *(u64*)(vTw + (vbase + (half * 3 + j) * 16 + lr) * 64 + mt * 16 + hi * 4) = pk;
        }
      }
    }
  }
  __syncthreads();

  // ---- P2: write Q,K into sQK (flipped layout: row=token, 4 consecutive ocols per lane)
  if (wv < 6) {
    const int wbase = wv * 64;
#pragma unroll
    for (int wt = 0; wt < 4; ++wt) {
      const int oc0 = wbase + wt * 16 + hi * 4;
      const f32x4 bq = *(const f32x4*)(bqkv + oc0);
      const float sc = (oc0 < 192) ? SCALE : 1.0f;
#pragma unroll
      for (int tt = 0; tt < 4; ++tt) {
        u64 pk = pack4(acc[wt][tt][0] + bq[0] * sc, acc[wt][tt][1] + bq[1] * sc,
                       acc[wt][tt][2] + bq[2] * sc, acc[wt][tt][3] + bq[3] * sc);
        *(u64*)&sQK[swz(tt * 16 + lr, oc0, 384)] = pk;
      }
    }
  }
  __syncthreads();

  // ---- P3: 24 slices (head h, row-quarter q), 3 per wave ----
  f32x4 S[3][4];
#pragma unroll
  for (int i = 0; i < 3; ++i) {
    const int s = wv + 8 * i, h3 = s >> 2, q = s & 3;
    short8x Aq = ldfrag(sQK, q * 16 + lr, h3 * 32 + hi * 8, 384);
#pragma unroll
    for (int nt = 0; nt < 4; ++nt) {
      short8x Bk = ldfrag(sQK, nt * 16 + lr, 192 + h3 * 32 + hi * 8, 384);
      S[i][nt] = MFMA(Aq, Bk, (f32x4){0.f, 0.f, 0.f, 0.f});
    }
#pragma unroll
    for (int r = 0; r < 4; ++r) {
      const int tI = q * 16 + hi * 4 + r;
      const int tri = tI >> 3, trj = tI & 7;
      const int ui = wi * 8 + tri, vi = wj * 8 + trj;
      const int rgi = (ui >= 248) + (ui >= 252), cgi = (vi >= 248) + (vi >= 252);
#pragma unroll
      for (int nt = 0; nt < 4; ++nt) {
        const int tJ = nt * 16 + lr;
        const int tci = tJ >> 3, tcj = tJ & 7;
        const int idx = (tri - tci + 7) * 15 + (trj - tcj + 7);
        float v = S[i][nt][r] + sRel[idx * 6 + h3];
        const int uj = wi * 8 + tci, vj = wj * 8 + tcj;
        const int rgj = (uj >= 248) + (uj >= 252), cgj = (vj >= 248) + (vj >= 252);
        if ((rgi != rgj) | (cgi != cgj)) v -= 100.0f;
        S[i][nt][r] = v;
      }
    }
#pragma unroll
    for (int r = 0; r < 4; ++r) {
      float mx = fmaxf(fmaxf(S[i][0][r], S[i][1][r]), fmaxf(S[i][2][r], S[i][3][r]));
      mx = fmaxf(mx, __shfl_xor(mx, 1));
      mx = fmaxf(mx, __shfl_xor(mx, 2));
      mx = fmaxf(mx, __shfl_xor(mx, 4));
      mx = fmaxf(mx, __shfl_xor(mx, 8));
      float sm = 0.f;
#pragma unroll
      for (int nt = 0; nt < 4; ++nt) { float e = __expf(S[i][nt][r] - mx); S[i][nt][r] = e; sm += e; }
      sm += __shfl_xor(sm, 1); sm += __shfl_xor(sm, 2);
      sm += __shfl_xor(sm, 4); sm += __shfl_xor(sm, 8);
      const float inv = 1.0f / sm;
#pragma unroll
      for (int nt = 0; nt < 4; ++nt) S[i][nt][r] *= inv;
    }
  }
  __syncthreads();  // all Q/K reads done

  // P write over Q,K region: P_h = [64 tok][64 key] at h*4096, swizzled ld=64
#pragma unroll
  for (int i = 0; i < 3; ++i) {
    const int s = wv + 8 * i, h3 = s >> 2, q = s & 3;
#pragma unroll
    for (int r = 0; r < 4; ++r)
#pragma unroll
      for (int nt = 0; nt < 4; ++nt)
        sQK[h3 * 4096 + swz(q * 16 + hi * 4 + r, nt * 16 + lr, 64)] = f2bf(S[i][nt][r]);
  }
  __syncthreads();

  // ---- P4: PV, 24 tiles (h, dcol-tile, tok-half), 3 per wave, flipped ----
  f32x4 oacc[3][2] = {};
#pragma unroll
  for (int i = 0; i < 3; ++i) {
    const int t = wv + 8 * i, h3 = t >> 2, dt = (t >> 1) & 1, tth = t & 1;
#pragma unroll
    for (int kk = 0; kk < 2; ++kk) {
      short8x Va = ldg8(vTw + (h3 * 32 + dt * 16 + lr) * 64 + kk * 32 + hi * 8);
#pragma unroll
      for (int t2 = 0; t2 < 2; ++t2) {
        short8x Pf = ldfrag(sQK + h3 * 4096, tth * 32 + t2 * 16 + lr, kk * 32 + hi * 8, 64);
        oacc[i][t2] = MFMA(Va, Pf, oacc[i][t2]);
      }
    }
  }
  __syncthreads();  // PV reads of P done

  // attn-out over P region: [64 tok][192 dcol] swizzled, b64 packed
#pragma unroll
  for (int i = 0; i < 3; ++i) {
    const int t = wv + 8 * i, h3 = t >> 2, dt = (t >> 1) & 1, tth = t & 1;
#pragma unroll
    for (int t2 = 0; t2 < 2; ++t2) {
      u64 pk = pack4(oacc[i][t2][0], oacc[i][t2][1], oacc[i][t2][2], oacc[i][t2][3]);
      *(u64*)&sQK[swz(tth * 32 + t2 * 16 + lr, h3 * 32 + dt * 16 + hi * 4, 192)] = pk;
    }
  }
  __syncthreads();

  // ---- P6: proj flipped + residual -> x1out. 12 wtiles over 8 waves
  {
    const int nw = (wv < 4) ? 2 : 1;
    const int wt0 = (wv < 4) ? wv * 2 : (4 + wv);
    f32x4 pacc[2][4] = {};
#pragma unroll
    for (int kk = 0; kk < 6; ++kk) {
      short8x Of[4];
#pragma unroll
      for (int tt = 0; tt < 4; ++tt) Of[tt] = ldfrag(sQK, tt * 16 + lr, kk * 32 + hi * 8, 192);
      for (int w2 = 0; w2 < nw; ++w2) {
        short8x Wp = ldg8(wp + ((wt0 + w2) * 16 + lr) * 192 + kk * 32 + hi * 8);
#pragma unroll
        for (int tt = 0; tt < 4; ++tt) pacc[w2][tt] = MFMA(Wp, Of[tt], pacc[w2][tt]);
      }
    }
    for (int w2 = 0; w2 < nw; ++w2) {
      const int oc0 = (wt0 + w2) * 16 + hi * 4;
      const f32x4 bb = *(const f32x4*)(bproj + oc0);
#pragma unroll
      for (int tt = 0; tt < 4; ++tt) {
        const int grow = sG[tt * 16 + lr];
        const f32x4 xv = *(const f32x4*)(x + grow * 192 + oc0);
        f32x4 o;
#pragma unroll
        for (int r = 0; r < 4; ++r) o[r] = xv[r] + pacc[w2][tt][r] + bb[r];
        *(f32x4*)(x1out + grow * 192 + oc0) = o;
      }
    }
  }
}

// ---------------- conv1 (1x1, 192->24 padded 32), MFMA ----------------
__global__ __launch_bounds__(256) void conv1_kernel(const u16* __restrict__ nx,
                                                    const u16* __restrict__ w1,
                                                    const float* __restrict__ b1,
                                                    float* __restrict__ y1) {
  const int tid = threadIdx.x, wv = tid >> 6, lane = tid & 63, lr = lane & 15, hi = lane >> 4;
  const int g0 = blockIdx.x * 64;
  const int mt = wv;
  short8x Af[6];
#pragma unroll
  for (int kk = 0; kk < 6; ++kk)
    Af[kk] = ldg8(nx + (g0 + mt * 16 + lr) * 192 + kk * 32 + hi * 8);
  const int bI = g0 >> 16;
  const int hw0 = g0 & 65535;
#pragma unroll
  for (int nt = 0; nt < 2; ++nt) {
    f32x4 acc = {0.f, 0.f, 0.f, 0.f};
#pragma unroll
    for (int kk = 0; kk < 6; ++kk) {
      short8x Bf = ldg8(w1 + (nt * 16 + lr) * 192 + kk * 32 + hi * 8);
      acc = MFMA(Af[kk], Bf, acc);
    }
    const int c = nt * 16 + lr;
    if (c < 24) {
      const float bb = b1[c];
#pragma unroll
      for (int r = 0; r < 4; ++r) {
        const int pix = hw0 + mt * 16 + hi * 4 + r;
        y1[(bI * 24 + c) * 65536 + pix] = acc[r] + bb;
      }
    }
  }
}

// ---------------- conv2 (3x3, 24->24), VALU ----------------
__global__ __launch_bounds__(256) void conv2_kernel(const float* __restrict__ y1,
                                                    const float* __restrict__ w2r,
                                                    const float* __restrict__ cb2,
                                                    u16* __restrict__ y2) {
  const int j = threadIdx.x;
  const int i = blockIdx.x & 255;
  const int b = blockIdx.x >> 8;
  float acc[24];
#pragma unroll
  for (int r = 0; r < 24; ++r) acc[r] = cb2[r];
  const float* base = y1 + b * 24 * 65536;
  for (int t = 0; t < 9; ++t) {
    const int dh = t / 3 - 1, dw = t % 3 - 1;
    const int ii = i + dh, jj = j + dw;
    const bool ok = (ii >= 0) & (ii < 256) & (jj >= 0) & (jj < 256);
    const int offc = ok ? (ii * 256 + jj) : 0;
    const float* wt = w2r + t * 576;
    float v[24];
#pragma unroll
    for (int ci = 0; ci < 24; ++ci) {
      float vv = base[ci * 65536 + offc];
      v[ci] = ok ? vv : 0.0f;
    }
#pragma unroll
    for (int ci = 0; ci < 24; ++ci)
#pragma unroll
      for (int co = 0; co < 24; ++co)
        acc[co] += v[ci] * wt[ci * 24 + co];
  }
  u16* o = y2 + (b * 65536 + i * 256 + j) * 32;
#pragma unroll
  for (int r = 0; r < 24; ++r) o[r] = f2bf(acc[r]);
  ((unsigned long long*)(o + 24))[0] = 0ull;
  ((unsigned long long*)(o + 24))[1] = 0ull;
}

// ---------------- conv3 (1x1, 24->192) + LeakyReLU + pooled sums ----------------
__global__ __launch_bounds__(256) void conv3_kernel(const u16* __restrict__ y2,
                                                    const u16* __restrict__ w3,
                                                    const float* __restrict__ b3,
                                                    u16* __restrict__ y,
                                                    float* __restrict__ pooled) {
  const int tid = threadIdx.x, wv = tid >> 6, lane = tid & 63, lr = lane & 15, hi = lane >> 4;
  const int g0 = blockIdx.x * 64;
  short8x Af[4];
#pragma unroll
  for (int mt = 0; mt < 4; ++mt)
    Af[mt] = ldg8(y2 + (g0 + mt * 16 + lr) * 32 + hi * 8);
  const int bI = g0 >> 16;
#pragma unroll
  for (int nt0 = 0; nt0 < 3; ++nt0) {
    const int c = (wv * 3 + nt0) * 16 + lr;
    short8x Bf = ldg8(w3 + c * 32 + hi * 8);
    const float bb = b3[c];
    float colsum = 0.f;
#pragma unroll
    for (int mt = 0; mt < 4; ++mt) {
      f32x4 acc = {0.f, 0.f, 0.f, 0.f};
      acc = MFMA(Af[mt], Bf, acc);
#pragma unroll
      for (int r = 0; r < 4; ++r) {
        float v = acc[r] + bb;
        v = (v >= 0.f) ? v : 0.2f * v;
        y[(g0 + mt * 16 + hi * 4 + r) * 192 + c] = f2bf(v);
        colsum += v;
      }
    }
    colsum += __shfl_xor(colsum, 16);
    colsum += __shfl_xor(colsum, 32);
    if (hi == 0) atomicAdd(&pooled[bI * 192 + c], colsum);
  }
}

// ---------------- SE gate ----------------
__global__ void se_kernel(const float* __restrict__ pooled, const float* __restrict__ w1,
                          const float* __restrict__ w2, float* __restrict__ wgt) {
  __shared__ float t[24];
  const int b = blockIdx.x, lane = threadIdx.x;
  if (lane < 24) {
    float s = 0.f;
    for (int c = 0; c < 192; ++c) s += pooled[b * 192 + c] * (1.0f / 65536.0f) * w1[lane * 192 + c];
    t[lane] = fmaxf(s, 0.0f);
  }
  __syncthreads();
  for (int c = lane; c < 192; c += 64) {
    float s = 0.f;
#pragma unroll
    for (int r = 0; r < 24; ++r) s += t[r] * w2[c * 24 + r];
    wgt[b * 192 + c] = 1.0f / (1.0f + __expf(-s));
  }
}

// ---------------- fused LN2 + MLP + residual + LCE add (R3 champion config) ----------------
// 64 rows/block, 12 waves, single sH buffer. LDS = 24 + 24 = 48 KB -> 2 blocks/CU.
__global__ __launch_bounds__(768, 6) void mlp_kernel(
    const float* x1, const float* __restrict__ g2, const float* __restrict__ b2,
    const u16* __restrict__ w1m, const float* __restrict__ bf1,
    const u16* __restrict__ w2m, const float* __restrict__ bf2,
    const u16* __restrict__ y, const float* __restrict__ wgt, float* out) {
  __shared__ u16 sN[64 * 192];
  __shared__ u16 sH[64 * 192];
  const int tid = threadIdx.x, wv = tid >> 6, lane = tid & 63, lr = lane & 15, hi = lane >> 4;
  const int g0 = blockIdx.x * 64;

  for (int row = wv; row < 64; row += 12) {
    const float* xr = x1 + (g0 + row) * 192;
    float v0 = xr[lane], v1 = xr[lane + 64], v2 = xr[lane + 128];
    float s = v0 + v1 + v2;
    for (int m = 1; m < 64; m <<= 1) s += __shfl_xor(s, m);
    const float mean = s * (1.0f / 192.0f);
    const float d0 = v0 - mean, d1 = v1 - mean, d2 = v2 - mean;
    float q = d0 * d0 + d1 * d1 + d2 * d2;
    for (int m = 1; m < 64; m <<= 1) q += __shfl_xor(q, m);
    const float rstd = rsqrtf(q * (1.0f / 192.0f) + 1e-5f);
    sN[swz(row, lane, 192)]       = f2bf(d0 * rstd * g2[lane] + b2[lane]);
    sN[swz(row, lane + 64, 192)]  = f2bf(d1 * rstd * g2[lane + 64] + b2[lane + 64]);
    sN[swz(row, lane + 128, 192)] = f2bf(d2 * rstd * g2[lane + 128] + b2[lane + 128]);
  }
  __syncthreads();

  f32x4 acc[4] = {};  // FC2 accumulators: wave owns out cols wv*16..+16
  for (int c = 0; c < 4; ++c) {
    // FC1 for hidden chunk c: wave owns 16 hidden cols
    const int hcol = c * 192 + wv * 16 + lr;
    f32x4 a1[4] = {};
#pragma unroll
    for (int kk = 0; kk < 6; ++kk) {
      short8x B = ldg8(w1m + hcol * 192 + kk * 32 + hi * 8);
#pragma unroll
      for (int mt = 0; mt < 4; ++mt)
        a1[mt] = MFMA(ldfrag(sN, mt * 16 + lr, kk * 32 + hi * 8, 192), B, a1[mt]);
    }
    if (c) __syncthreads();  // fc2(c-1) readers done before overwriting sH
    const float bb1 = bf1[hcol];
#pragma unroll
    for (int mt = 0; mt < 4; ++mt)
#pragma unroll
      for (int r = 0; r < 4; ++r)
        sH[swz(mt * 16 + hi * 4 + r, wv * 16 + lr, 192)] = f2bf(gelu_f(a1[mt][r] + bb1));
    __syncthreads();
    // FC2 partial over this chunk's K
#pragma unroll
    for (int kk = 0; kk < 6; ++kk) {
      short8x B = ldg8(w2m + (wv * 16 + lr) * 768 + c * 192 + kk * 32 + hi * 8);
#pragma unroll
      for (int mt = 0; mt < 4; ++mt)
        acc[mt] = MFMA(ldfrag(sH, mt * 16 + lr, kk * 32 + hi * 8, 192), B, acc[mt]);
    }
  }

  const int bI = g0 >> 16;
  const int ocol = wv * 16 + lr;
  const float bb = bf2[ocol];
  const float wg = wgt[bI * 192 + ocol];
#pragma unroll
  for (int mt = 0; mt < 4; ++mt)
#pragma unroll
    for (int r = 0; r < 4; ++r) {
      const int grow = g0 + mt * 16 + hi * 4 + r;
      const float lc = bf2f(y[grow * 192 + ocol]) * wg;
      out[grow * 192 + ocol] = x1[grow * 192 + ocol] + acc[mt][r] + bb + lc;
    }
}

extern "C" void kernel_launch(void* const* d_in, const int* in_sizes, int n_in,
                              void* d_out, int out_size, void* d_ws, size_t ws_size,
                              hipStream_t stream) {
  const float* x     = (const float*)d_in[0];
  const float* ln1g  = (const float*)d_in[1];
  const float* ln1b  = (const float*)d_in[2];
  const float* wqkv  = (const float*)d_in[3];
  const float* bqkv  = (const float*)d_in[4];
  const float* rel   = (const float*)d_in[5];
  const float* wproj = (const float*)d_in[6];
  const float* bproj = (const float*)d_in[7];
  const float* ln2g  = (const float*)d_in[8];
  const float* ln2b  = (const float*)d_in[9];
  const float* wfc1  = (const float*)d_in[10];
  const float* bfc1  = (const float*)d_in[11];
  const float* wfc2  = (const float*)d_in[12];
  const float* bfc2  = (const float*)d_in[13];
  const float* c1w   = (const float*)d_in[14];
  const float* c1b   = (const float*)d_in[15];
  const float* c2w   = (const float*)d_in[16];
  const float* c2b   = (const float*)d_in[17];
  const float* c3w   = (const float*)d_in[18];
  const float* c3b   = (const float*)d_in[19];
  const float* sew1  = (const float*)d_in[20];
  const float* sew2  = (const float*)d_in[21];

  char* ws = (char*)d_ws;
  u16*   nx   = (u16*)(ws + 0);
  float* y1   = (float*)(ws + 100663296);
  u16*   y2   = (u16*)(ws + 125829120);
  u16*   yb   = (u16*)(ws + 142606336);   // LCE output; ALSO reused as vT during attn (attn < conv3)
  u16*   wq   = (u16*)(ws + 243269632);
  u16*   wp   = (u16*)(ws + 243490816);
  u16*   w1m  = (u16*)(ws + 243564544);
  u16*   w2m  = (u16*)(ws + 243859456);
  u16*   cw1  = (u16*)(ws + 244154368);
  u16*   cw3  = (u16*)(ws + 244166656);
  float* w2r  = (float*)(ws + 244178944);
  float* pool = (float*)(ws + 244199680);
  float* wgt  = (float*)(ws + 244202752);
  float* out  = (float*)d_out;
  u16*   vT   = yb;

  hipMemsetAsync(pool, 0, 3072, stream);
  cvt_kernel<<<1797, 256, 0, stream>>>(wqkv, wproj, wfc1, wfc2, c1w, c3w, c2w,
                                       wq, wp, w1m, w2m, cw1, cw3, w2r);
  ln1_kernel<<<65536, 256, 0, stream>>>(x, ln1g, ln1b, nx);
  attn_kernel<<<4096, 512, 0, stream>>>(x, nx, wq, bqkv, rel, wp, bproj, vT, out);
  conv1_kernel<<<4096, 256, 0, stream>>>(nx, cw1, c1b, y1);
  conv2_kernel<<<1024, 256, 0, stream>>>(y1, w2r, c2b, y2);
  conv3_kernel<<<4096, 256, 0, stream>>>(y2, cw3, c3b, yb, pool);
  se_kernel<<<4, 64, 0, stream>>>(pool, sew1, sew2, wgt);
  mlp_kernel<<<4096, 768, 0, stream>>>(out, ln2g, ln2b, w1m, bfc1, w2m, bfc2, yb, wgt, out);
}